// Round 2
// baseline (6347.808 us; speedup 1.0000x reference)
//
#include <hip/hip_runtime.h>
#include <hip/hip_bf16.h>

#define B 2
#define L 2048
#define D 1024
#define H 16
#define HD 64
#define LH 8
#define NEG_INF -1e30f

typedef __hip_bfloat16 bf16;

template<typename T> struct IsF32;
template<> struct IsF32<float> { static constexpr int value = 1; };
template<> struct IsF32<bf16>  { static constexpr int value = 0; };

__device__ __forceinline__ float ldf(const float* p, size_t i) { return p[i]; }
__device__ __forceinline__ float ldf(const bf16* p, size_t i) { return __bfloat162float(p[i]); }
__device__ __forceinline__ void stf(float* p, size_t i, float v) { p[i] = v; }
__device__ __forceinline__ void stf(bf16* p, size_t i, float v) { p[i] = __float2bfloat16(v); }

// Runtime dtype detection: an fp32 array reinterpreted as u16 pairs puts fp32
// mantissa bits into the bf16 exponent field of every low half-word -> values
// with exponent-field >= 170 appear with prob ~1/3 per low half. Genuine bf16
// N(0,1) data never has exponent-field above ~130. flag=1 -> inputs are fp32.
__global__ void detect_dtype_kernel(const unsigned short* __restrict__ x,
                                    int* __restrict__ flag) {
  int bad = 0;
  for (int i = threadIdx.x; i < 1024; i += 64) {
    if (((x[i] >> 7) & 0xFF) >= 170) bad = 1;
  }
  unsigned long long m = __ballot(bad);
  if (threadIdx.x == 0) *flag = (m != 0ULL) ? 1 : 0;
}

// ---------------- Kernel 1: fused QKV projection ----------------
// grid (B*L, D/256), block 256. Writes fp32 Q/K/V in [B,H,L,HD] layout.
template<typename T>
__global__ void proj_qkv_kernel(const int* __restrict__ flag,
                                const T* __restrict__ x,
                                const T* __restrict__ Wq, const T* __restrict__ bq,
                                const T* __restrict__ Wk, const T* __restrict__ bk,
                                const T* __restrict__ Wv, const T* __restrict__ bv,
                                float* __restrict__ Q, float* __restrict__ K,
                                float* __restrict__ V) {
  if (*flag != IsF32<T>::value) return;
  const int row = blockIdx.x;                       // 0 .. B*L-1
  const int col = blockIdx.y * 256 + threadIdx.x;   // 0 .. D-1
  __shared__ float xs[D];
  for (int i = threadIdx.x; i < D; i += 256)
    xs[i] = ldf(x, (size_t)row * D + i);
  __syncthreads();
  float aq = 0.f, ak = 0.f, av = 0.f;
  for (int i = 0; i < D; ++i) {
    const float xv = xs[i];
    aq = fmaf(xv, ldf(Wq, (size_t)i * D + col), aq);
    ak = fmaf(xv, ldf(Wk, (size_t)i * D + col), ak);
    av = fmaf(xv, ldf(Wv, (size_t)i * D + col), av);
  }
  aq += ldf(bq, col);
  ak += ldf(bk, col);
  av += ldf(bv, col);
  const int b = row / L, l = row % L;
  const int h = col >> 6, hd = col & 63;
  const size_t idx = ((size_t)(b * H + h) * L + l) * HD + hd;
  Q[idx] = aq; K[idx] = ak; V[idx] = av;
}

// ---------------- Kernel 2: attention ----------------
// grid (L, H, B), block 64 (one wave). One block per (b,h,q) query row.
template<typename T>
__global__ void attn_kernel(const int* __restrict__ flag,
                            const float* __restrict__ Q, const float* __restrict__ K,
                            const float* __restrict__ V,
                            const T* __restrict__ lscale_p, const T* __restrict__ gscale_p,
                            T* __restrict__ attn_l, T* __restrict__ attn_g,
                            float* __restrict__ AO) {
  if (*flag != IsF32<T>::value) return;
  const int q = blockIdx.x;
  const int h = blockIdx.y;
  const int b = blockIdx.z;
  const int t = threadIdx.x;   // 0..63

  const float* Kbh = K + (size_t)(b * H + h) * L * HD;
  const float* Vbh = V + (size_t)(b * H + h) * L * HD;
  const float* Qrow = Q + ((size_t)(b * H + h) * L + q) * HD;

  __shared__ float qs[HD];
  __shared__ float ks[64][HD + 1];   // +1 pad to break bank aliasing
  __shared__ float ps[L];

  qs[t] = Qrow[t];

  const bool is_local = (h < LH);
  const float scale = is_local ? ldf(lscale_p, 0) : ldf(gscale_p, 0);
  const float inv_sqrt = 0.125f;   // 1/sqrt(64)

  float s[L / 64];   // 32 scores per thread: key k = kt*64 + t

  for (int kt = 0; kt < L / 64; ++kt) {
    // stage 64 keys into LDS (coalesced global reads)
    for (int j = 0; j < 64; ++j)
      ks[j][t] = Kbh[(size_t)(kt * 64 + j) * HD + t];
    __syncthreads();
    float acc = 0.f;
    #pragma unroll
    for (int d = 0; d < HD; ++d)
      acc = fmaf(qs[d], ks[t][d], acc);
    acc *= inv_sqrt;
    const int k = kt * 64 + t;
    if (is_local) {
      s[kt] = (k <= q) ? acc * scale : NEG_INF;
    } else {
      s[kt] = acc * scale;
    }
    __syncthreads();   // before overwriting ks next iteration
  }

  // row max (wave-64 reduction)
  float m = NEG_INF;
  #pragma unroll
  for (int kt = 0; kt < L / 64; ++kt) m = fmaxf(m, s[kt]);
  #pragma unroll
  for (int o = 32; o > 0; o >>= 1) m = fmaxf(m, __shfl_xor(m, o, 64));

  // exp + sum
  float lsum = 0.f;
  #pragma unroll
  for (int kt = 0; kt < L / 64; ++kt) {
    s[kt] = __expf(s[kt] - m);   // masked -1e30 -> exp -> 0
    lsum += s[kt];
  }
  #pragma unroll
  for (int o = 32; o > 0; o >>= 1) lsum += __shfl_xor(lsum, o, 64);
  const float inv_sum = 1.0f / lsum;

  // normalize, write attn row + stash probs in LDS
  const size_t arow = ((size_t)(b * LH + (is_local ? h : h - LH)) * L + q) * L;
  T* attn_out = is_local ? attn_l : attn_g;
  #pragma unroll
  for (int kt = 0; kt < L / 64; ++kt) {
    const int k = kt * 64 + t;
    const float p = s[kt] * inv_sum;
    ps[k] = p;
    stf(attn_out, arow + k, p);
  }
  __syncthreads();

  // out[d] = sum_k p[k] * V[k][d]; thread t handles d = t
  float acc = 0.f;
  for (int k = 0; k < L; ++k)
    acc = fmaf(ps[k], Vbh[(size_t)k * HD + t], acc);
  AO[((size_t)b * L + q) * D + h * HD + t] = acc;
}

// ---------------- Kernel 3: output projection ----------------
// grid (B*L, D/256), block 256.
template<typename T>
__global__ void out_proj_kernel(const int* __restrict__ flag,
                                const float* __restrict__ AO,
                                const T* __restrict__ Wo, const T* __restrict__ bo,
                                T* __restrict__ out) {
  if (*flag != IsF32<T>::value) return;
  const int row = blockIdx.x;
  const int col = blockIdx.y * 256 + threadIdx.x;
  __shared__ float xs[D];
  for (int i = threadIdx.x; i < D; i += 256)
    xs[i] = AO[(size_t)row * D + i];
  __syncthreads();
  float acc = 0.f;
  for (int i = 0; i < D; ++i)
    acc = fmaf(xs[i], ldf(Wo, (size_t)i * D + col), acc);
  acc += ldf(bo, col);
  stf(out, (size_t)row * D + col, acc);
}

template<typename T>
static void launch_path(void* const* d_in, void* d_out, void* d_ws, hipStream_t stream) {
  const size_t NQKV = (size_t)B * H * L * HD;   // 4,194,304
  const int* flag = (const int*)d_ws;
  float* Q  = (float*)((char*)d_ws + 256);
  float* K  = Q + NQKV;
  float* V  = K + NQKV;
  float* AO = V + NQKV;

  const T* x  = (const T*)d_in[0];
  const T* Wq = (const T*)d_in[1];
  const T* bq = (const T*)d_in[2];
  const T* Wk = (const T*)d_in[3];
  const T* bk = (const T*)d_in[4];
  const T* Wv = (const T*)d_in[5];
  const T* bv = (const T*)d_in[6];
  const T* Wo = (const T*)d_in[7];
  const T* bo = (const T*)d_in[8];
  const T* ls = (const T*)d_in[9];
  const T* gs = (const T*)d_in[10];

  T* out0   = (T*)d_out;
  T* attn_l = out0 + (size_t)B * L * D;
  T* attn_g = attn_l + (size_t)B * LH * L * L;

  proj_qkv_kernel<T><<<dim3(B * L, D / 256), 256, 0, stream>>>(
      flag, x, Wq, bq, Wk, bk, Wv, bv, Q, K, V);
  attn_kernel<T><<<dim3(L, H, B), 64, 0, stream>>>(
      flag, Q, K, V, ls, gs, attn_l, attn_g, AO);
  out_proj_kernel<T><<<dim3(B * L, D / 256), 256, 0, stream>>>(
      flag, AO, Wo, bo, out0);
}

extern "C" void kernel_launch(void* const* d_in, const int* in_sizes, int n_in,
                              void* d_out, int out_size, void* d_ws, size_t ws_size,
                              hipStream_t stream) {
  int* flag = (int*)d_ws;
  detect_dtype_kernel<<<1, 64, 0, stream>>>((const unsigned short*)d_in[0], flag);
  launch_path<float>(d_in, d_out, d_ws, stream);
  launch_path<bf16>(d_in, d_out, d_ws, stream);
}